// Round 1
// baseline (3995.163 us; speedup 1.0000x reference)
//
#include <hip/hip_runtime.h>
#include <float.h>

#define D_DIM 512
#define BM 64
#define BN 64
#define BK 32
#define PADA 4

// ---------------------------------------------------------------------------
// Per-row reciprocal L2 norm: r[row] = 1 / max(||X[row,:]||_2, 1e-12)
// One wave (64 lanes) per row; 4 rows per 256-thread block. D fixed at 512.
// ---------------------------------------------------------------------------
__global__ __launch_bounds__(256) void rnorm_kernel(const float* __restrict__ X,
                                                    float* __restrict__ r, int R) {
    int row = blockIdx.x * 4 + (threadIdx.x >> 6);
    if (row >= R) return;
    int lane = threadIdx.x & 63;
    const float* x = X + (size_t)row * D_DIM;
    float s = 0.f;
#pragma unroll
    for (int t = 0; t < 2; ++t) {
        float4 v = *(const float4*)(x + (t * 64 + lane) * 4);
        s += v.x * v.x + v.y * v.y + v.z * v.z + v.w * v.w;
    }
#pragma unroll
    for (int off = 32; off; off >>= 1) s += __shfl_xor(s, off);
    if (lane == 0) {
        float n = sqrtf(s);
        r[row] = 1.0f / fmaxf(n, 1e-12f);
    }
}

// ---------------------------------------------------------------------------
// sim[b,p] = dot(Z[b,:], P[p,:]) * rz[b] * rp[p]
// 64x64 output tile per 256-thread block; 4x4 accumulator per thread.
// A/B staged in LDS transposed ([k][m]) so fragments are float4 LDS reads.
// ---------------------------------------------------------------------------
__global__ __launch_bounds__(256) void gemm_sim_kernel(const float* __restrict__ Z,
                                                       const float* __restrict__ Pm,
                                                       const float* __restrict__ rz,
                                                       const float* __restrict__ rp,
                                                       float* __restrict__ sim,
                                                       int Pn) {
    __shared__ float As[BK][BM + PADA];
    __shared__ float Bs[BK][BN + PADA];
    const int bm = blockIdx.y * BM;
    const int bn = blockIdx.x * BN;
    const int tid = threadIdx.x;
    const int tx = tid & 15;
    const int ty = tid >> 4;

    float acc[4][4] = {};

    for (int k0 = 0; k0 < D_DIM; k0 += BK) {
        // Stage 64x32 tiles of A and B (transposed into LDS).
        // 2048 floats each = 256 threads x 2 float4.
#pragma unroll
        for (int l = 0; l < 2; ++l) {
            int f = tid + l * 256;
            int row = f >> 3;   // 0..63
            int c4  = f & 7;    // 0..7 (float4 column within the 32-wide K slab)
            float4 a = *(const float4*)(Z + (size_t)(bm + row) * D_DIM + k0 + c4 * 4);
            As[c4 * 4 + 0][row] = a.x;
            As[c4 * 4 + 1][row] = a.y;
            As[c4 * 4 + 2][row] = a.z;
            As[c4 * 4 + 3][row] = a.w;
            float4 b = *(const float4*)(Pm + (size_t)(bn + row) * D_DIM + k0 + c4 * 4);
            Bs[c4 * 4 + 0][row] = b.x;
            Bs[c4 * 4 + 1][row] = b.y;
            Bs[c4 * 4 + 2][row] = b.z;
            Bs[c4 * 4 + 3][row] = b.w;
        }
        __syncthreads();
#pragma unroll
        for (int kk = 0; kk < BK; ++kk) {
            float4 a4 = *(const float4*)&As[kk][ty * 4];
            float4 b4 = *(const float4*)&Bs[kk][tx * 4];
            float av[4] = {a4.x, a4.y, a4.z, a4.w};
            float bv[4] = {b4.x, b4.y, b4.z, b4.w};
#pragma unroll
            for (int i = 0; i < 4; ++i)
#pragma unroll
                for (int j = 0; j < 4; ++j)
                    acc[i][j] = fmaf(av[i], bv[j], acc[i][j]);
        }
        __syncthreads();
    }

    const int orow = bm + ty * 4;
    const int ocol = bn + tx * 4;
    float rpv[4];
#pragma unroll
    for (int j = 0; j < 4; ++j) rpv[j] = rp[ocol + j];
#pragma unroll
    for (int i = 0; i < 4; ++i) {
        float rs = rz[orow + i];
        float4 o;
        o.x = acc[i][0] * rs * rpv[0];
        o.y = acc[i][1] * rs * rpv[1];
        o.z = acc[i][2] * rs * rpv[2];
        o.w = acc[i][3] * rs * rpv[3];
        *(float4*)&sim[(size_t)(orow + i) * Pn + ocol] = o;
    }
}

// ---------------------------------------------------------------------------
// Top-3 per row. One wave per row (4 rows / 256-thread block).
// Each lane keeps a sorted local top-3 over its strided slice, then 3 rounds
// of butterfly arg-max (ties -> lower index, matching lax.top_k) with pop.
// Indices are written as float (exact up to 2^24).
// ---------------------------------------------------------------------------
__global__ __launch_bounds__(256) void topk3_kernel(const float* __restrict__ sim,
                                                    float* __restrict__ oidx,
                                                    float* __restrict__ oval,
                                                    int Pn) {
    int row = blockIdx.x * 4 + (threadIdx.x >> 6);
    int lane = threadIdx.x & 63;
    const float* rptr = sim + (size_t)row * Pn;

    float v0 = -FLT_MAX, v1 = -FLT_MAX, v2 = -FLT_MAX;
    int i0 = -1, i1 = -1, i2 = -1;

    const int iters = Pn / 256;   // 64 lanes x float4 per iteration
    for (int t = 0; t < iters; ++t) {
        int base = t * 256 + lane * 4;
        float4 v = *(const float4*)(rptr + base);
        float vals[4] = {v.x, v.y, v.z, v.w};
#pragma unroll
        for (int e = 0; e < 4; ++e) {
            float val = vals[e];
            int idx = base + e;
            if (val > v2) {
                if (val > v1) {
                    if (val > v0) {
                        v2 = v1; i2 = i1; v1 = v0; i1 = i0; v0 = val; i0 = idx;
                    } else {
                        v2 = v1; i2 = i1; v1 = val; i1 = idx;
                    }
                } else {
                    v2 = val; i2 = idx;
                }
            }
        }
    }

#pragma unroll
    for (int k = 0; k < 3; ++k) {
        float bv = v0;
        int bi = i0;
#pragma unroll
        for (int off = 32; off; off >>= 1) {
            float ov = __shfl_xor(bv, off);
            int oi = __shfl_xor(bi, off);
            if (ov > bv || (ov == bv && oi >= 0 && (unsigned)oi < (unsigned)bi)) {
                bv = ov;
                bi = oi;
            }
        }
        // Exactly one lane owns index bi; pop its head.
        if (bi == i0) {
            v0 = v1; i0 = i1;
            v1 = v2; i1 = i2;
            v2 = -FLT_MAX; i2 = -1;
        }
        if (lane == 0) {
            oidx[(size_t)row * 3 + k] = (float)bi;
            oval[(size_t)row * 3 + k] = bv;
        }
    }
}

extern "C" void kernel_launch(void* const* d_in, const int* in_sizes, int n_in,
                              void* d_out, int out_size, void* d_ws, size_t ws_size,
                              hipStream_t stream) {
    const float* Z  = (const float*)d_in[0];   // [B, 512]
    const float* Pm = (const float*)d_in[1];   // [P, 512]
    const int B  = in_sizes[0] / D_DIM;        // 8192
    const int Pn = in_sizes[1] / D_DIM;        // 32768

    float* sim  = (float*)d_out;                       // [B, P]
    float* oidx = sim + (size_t)B * Pn;                // [B, 3] (as float)
    float* oval = oidx + (size_t)B * 3;                // [B, 3]

    float* rz = (float*)d_ws;                          // [B]
    float* rp = rz + B;                                // [P]

    rnorm_kernel<<<B / 4, 256, 0, stream>>>(Z, rz, B);
    rnorm_kernel<<<Pn / 4, 256, 0, stream>>>(Pm, rp, Pn);

    dim3 grid(Pn / BN, B / BM);
    gemm_sim_kernel<<<grid, 256, 0, stream>>>(Z, Pm, rz, rp, sim, Pn);

    topk3_kernel<<<B / 4, 256, 0, stream>>>(sim, oidx, oval, Pn);
}

// Round 2
// 1571.394 us; speedup vs baseline: 2.5424x; 2.5424x over previous
//
#include <hip/hip_runtime.h>
#include <float.h>
#include <stdint.h>

#define D_DIM 512

typedef __attribute__((ext_vector_type(8))) short bf16x8;
typedef __attribute__((ext_vector_type(4))) float f32x4;

// ---------------------------------------------------------------------------
// Per-row reciprocal L2 norm: r[row] = 1 / max(||X[row,:]||, 1e-12)
// ---------------------------------------------------------------------------
__global__ __launch_bounds__(256) void rnorm_kernel(const float* __restrict__ X,
                                                    float* __restrict__ r, int R) {
    int row = blockIdx.x * 4 + (threadIdx.x >> 6);
    if (row >= R) return;
    int lane = threadIdx.x & 63;
    const float* x = X + (size_t)row * D_DIM;
    float s = 0.f;
#pragma unroll
    for (int t = 0; t < 2; ++t) {
        float4 v = *(const float4*)(x + (t * 64 + lane) * 4);
        s += v.x * v.x + v.y * v.y + v.z * v.z + v.w * v.w;
    }
#pragma unroll
    for (int off = 32; off; off >>= 1) s += __shfl_xor(s, off);
    if (lane == 0) r[row] = 1.0f / fmaxf(sqrtf(s), 1e-12f);
}

// round-half-up f32->bf16, pack two into one u32 (a = lower k, b = upper k)
__device__ __forceinline__ uint32_t pk_bf16(float a, float b) {
    uint32_t ua = __builtin_bit_cast(uint32_t, a) + 0x8000u;
    uint32_t ub = __builtin_bit_cast(uint32_t, b) + 0x8000u;
    return (ua >> 16) | (ub & 0xFFFF0000u);
}

// ---------------------------------------------------------------------------
// bf16 MFMA GEMM: sim[b,p] = (Z[b,:].P[p,:]) * rz[b] * rp[p]
// 128x128 tile, 4 waves (2x2), 4x4 frags of mfma_f32_16x16x32_bf16, BK=64.
// f32 loaded from global, converted to bf16 in regs, XOR-swizzled ds_write.
// ---------------------------------------------------------------------------
__global__ __launch_bounds__(256, 2) void gemm_bf16_sim(const float* __restrict__ Z,
        const float* __restrict__ Pm, const float* __restrict__ rz,
        const float* __restrict__ rp, float* __restrict__ sim, int Pn) {
    __shared__ uint4 As16[1024];  // 128 rows x 64 bf16 (128B), swizzled
    __shared__ uint4 Bs16[1024];

    // XCD-aware mapping: XCD x owns M-band [x*8, x*8+8); walk N-major inside.
    int bi = blockIdx.x;
    int mb, nb;
    if (gridDim.x == 16384) {
        int xcd = bi & 7;
        int r = bi >> 3;
        mb = xcd * 8 + (r & 7);   // 0..63
        nb = r >> 3;              // 0..255
    } else {
        nb = bi % (Pn / 128);
        mb = bi / (Pn / 128);
    }
    const int bm = mb * 128, bn = nb * 128;

    const int tid = threadIdx.x;
    const int srow = tid >> 1;        // staged row 0..127
    const int half = tid & 1;         // which 32-f32 half of the row
    const float* aP = Z  + (size_t)(bm + srow) * D_DIM + half * 32;
    const float* bP = Pm + (size_t)(bn + srow) * D_DIM + half * 32;

    const int lane = tid & 63;
    const int wid = tid >> 6;
    const int wr = wid >> 1, wc = wid & 1;
    const int ln15 = lane & 15, hi = lane >> 4;

    f32x4 acc[4][4] = {};

    float4 f[8], g[8];
#pragma unroll
    for (int q = 0; q < 8; ++q) {
        f[q] = *(const float4*)(aP + q * 4);
        g[q] = *(const float4*)(bP + q * 4);
    }

#pragma unroll 1
    for (int s = 0; s < 8; ++s) {
        // convert regs -> bf16, swizzled LDS write (4x b128 each for A and B)
#pragma unroll
        for (int q8 = 0; q8 < 4; ++q8) {
            uint4 wa, wb;
            wa.x = pk_bf16(f[2*q8].x,   f[2*q8].y);
            wa.y = pk_bf16(f[2*q8].z,   f[2*q8].w);
            wa.z = pk_bf16(f[2*q8+1].x, f[2*q8+1].y);
            wa.w = pk_bf16(f[2*q8+1].z, f[2*q8+1].w);
            wb.x = pk_bf16(g[2*q8].x,   g[2*q8].y);
            wb.y = pk_bf16(g[2*q8].z,   g[2*q8].w);
            wb.z = pk_bf16(g[2*q8+1].x, g[2*q8+1].y);
            wb.w = pk_bf16(g[2*q8+1].z, g[2*q8+1].w);
            int colByte = half * 64 + q8 * 16;
            int idx = srow * 8 + ((colByte ^ ((srow & 7) << 4)) >> 4);
            As16[idx] = wa;
            Bs16[idx] = wb;
        }
        __syncthreads();
        // prefetch next K-tile under the MFMA phase
        if (s < 7) {
            int k0 = (s + 1) * 64;
#pragma unroll
            for (int q = 0; q < 8; ++q) {
                f[q] = *(const float4*)(aP + k0 + q * 4);
                g[q] = *(const float4*)(bP + k0 + q * 4);
            }
        }
#pragma unroll
        for (int kk = 0; kk < 2; ++kk) {
            bf16x8 av[4], bv[4];
            const int cb = kk * 64 + hi * 16;
#pragma unroll
            for (int t = 0; t < 4; ++t) {
                int arow = wr * 64 + t * 16 + ln15;
                av[t] = __builtin_bit_cast(bf16x8,
                        As16[arow * 8 + ((cb ^ ((arow & 7) << 4)) >> 4)]);
                int brow = wc * 64 + t * 16 + ln15;
                bv[t] = __builtin_bit_cast(bf16x8,
                        Bs16[brow * 8 + ((cb ^ ((brow & 7) << 4)) >> 4)]);
            }
#pragma unroll
            for (int i = 0; i < 4; ++i)
#pragma unroll
                for (int j = 0; j < 4; ++j)
                    acc[i][j] = __builtin_amdgcn_mfma_f32_16x16x32_bf16(
                        av[i], bv[j], acc[i][j], 0, 0, 0);
        }
        __syncthreads();
    }

    // epilogue: scale by rz*rp; C/D layout col=lane&15, row=(lane>>4)*4+reg
    float rpv[4];
#pragma unroll
    for (int j = 0; j < 4; ++j) rpv[j] = rp[bn + wc * 64 + j * 16 + ln15];
#pragma unroll
    for (int i = 0; i < 4; ++i) {
#pragma unroll
        for (int rr = 0; rr < 4; ++rr) {
            int row = bm + wr * 64 + i * 16 + hi * 4 + rr;
            float rzv = rz[row];
#pragma unroll
            for (int j = 0; j < 4; ++j) {
                int col = bn + wc * 64 + j * 16 + ln15;
                sim[(size_t)row * Pn + col] = acc[i][j][rr] * rzv * rpv[j];
            }
        }
    }
}

// ---------------------------------------------------------------------------
// Top-3 with exact refinement. One wave per row:
//  1) per-lane sorted top-8 over its 512-elem strided slice of sim
//  2) 8 rounds of butterfly arg-max (+pop) -> global top-8 candidates
//  3) recompute the 8 dots exactly in f32 from raw Z,P (x rz x rp)
//  4) rank top-3 by exact value (ties -> lower index, matching lax.top_k)
// ---------------------------------------------------------------------------
__global__ __launch_bounds__(256) void topk_refine(const float* __restrict__ sim,
        const float* __restrict__ Z, const float* __restrict__ Pm,
        const float* __restrict__ rz, const float* __restrict__ rp,
        float* __restrict__ oidx, float* __restrict__ oval, int Pn) {
    int row = blockIdx.x * 4 + (threadIdx.x >> 6);
    int lane = threadIdx.x & 63;
    const float* rptr = sim + (size_t)row * Pn;

    float v[8]; int ix[8];
#pragma unroll
    for (int j = 0; j < 8; ++j) { v[j] = -FLT_MAX; ix[j] = -1; }

    const int iters = Pn >> 8;
    for (int t = 0; t < iters; ++t) {
        int base = t * 256 + lane * 4;
        float4 q = *(const float4*)(rptr + base);
        float vals[4] = {q.x, q.y, q.z, q.w};
#pragma unroll
        for (int e = 0; e < 4; ++e) {
            float val = vals[e];
            if (val > v[7]) {
                int idx = base + e;
                int pos = 7;
#pragma unroll
                for (int j = 6; j >= 0; --j) {
                    if (val > v[j]) { v[j+1] = v[j]; ix[j+1] = ix[j]; pos = j; }
                }
                v[pos] = val; ix[pos] = idx;
            }
        }
    }

    int cand[8];
#pragma unroll
    for (int k = 0; k < 8; ++k) {
        float bv = v[0]; int bi2 = ix[0];
#pragma unroll
        for (int off = 32; off; off >>= 1) {
            float ov = __shfl_xor(bv, off);
            int oi = __shfl_xor(bi2, off);
            if (ov > bv || (ov == bv && oi >= 0 && (unsigned)oi < (unsigned)bi2)) {
                bv = ov; bi2 = oi;
            }
        }
        cand[k] = bi2;
        if (bi2 == ix[0]) {  // pop owner's head
#pragma unroll
            for (int j = 0; j < 7; ++j) { v[j] = v[j+1]; ix[j] = ix[j+1]; }
            v[7] = -FLT_MAX; ix[7] = -1;
        }
    }

    // exact f32 recompute of the 8 candidate similarities
    float zv[8];
    const float* zrow = Z + (size_t)row * D_DIM + lane * 8;
#pragma unroll
    for (int j = 0; j < 8; ++j) zv[j] = zrow[j];
    float rzv = rz[row];

    float ex[8];
#pragma unroll
    for (int c = 0; c < 8; ++c) {
        int idx = cand[c];
        const float* prow = Pm + (size_t)idx * D_DIM + lane * 8;
        float s = 0.f;
#pragma unroll
        for (int j = 0; j < 8; ++j) s += zv[j] * prow[j];
#pragma unroll
        for (int off = 32; off; off >>= 1) s += __shfl_xor(s, off);
        ex[c] = s * rzv * rp[idx];
    }

    bool used[8] = {};
#pragma unroll
    for (int k = 0; k < 3; ++k) {
        float bv = -FLT_MAX; int bi2 = Pn; int bc = 0;
#pragma unroll
        for (int c = 0; c < 8; ++c) {
            if (!used[c] && (ex[c] > bv || (ex[c] == bv && cand[c] < bi2))) {
                bv = ex[c]; bi2 = cand[c]; bc = c;
            }
        }
        used[bc] = true;
        if (lane == 0) {
            oidx[(size_t)row * 3 + k] = (float)bi2;
            oval[(size_t)row * 3 + k] = bv;
        }
    }
}

extern "C" void kernel_launch(void* const* d_in, const int* in_sizes, int n_in,
                              void* d_out, int out_size, void* d_ws, size_t ws_size,
                              hipStream_t stream) {
    const float* Z  = (const float*)d_in[0];   // [B, 512]
    const float* Pm = (const float*)d_in[1];   // [P, 512]
    const int B  = in_sizes[0] / D_DIM;        // 8192
    const int Pn = in_sizes[1] / D_DIM;        // 32768

    float* sim  = (float*)d_out;
    float* oidx = sim + (size_t)B * Pn;
    float* oval = oidx + (size_t)B * 3;

    float* rz = (float*)d_ws;
    float* rp = rz + B;

    rnorm_kernel<<<B / 4, 256, 0, stream>>>(Z, rz, B);
    rnorm_kernel<<<Pn / 4, 256, 0, stream>>>(Pm, rp, Pn);

    gemm_bf16_sim<<<(B / 128) * (Pn / 128), 256, 0, stream>>>(Z, Pm, rz, rp, sim, Pn);

    topk_refine<<<B / 4, 256, 0, stream>>>(sim, Z, Pm, rz, rp, oidx, oval, Pn);
}

// Round 3
// 873.317 us; speedup vs baseline: 4.5747x; 1.7993x over previous
//
#include <hip/hip_runtime.h>
#include <float.h>
#include <stdint.h>

#define D_DIM 512

typedef __attribute__((ext_vector_type(8))) short bf16x8;
typedef __attribute__((ext_vector_type(4))) float f32x4;

// async global->LDS, 16B per lane (linear LDS dest: wave base + lane*16)
#define GLD_LDS16(g, l)                                              \
    __builtin_amdgcn_global_load_lds(                                \
        (const __attribute__((address_space(1))) void*)(g),          \
        (__attribute__((address_space(3))) void*)(l), 16, 0, 0)

// round-half-up f32->bf16, pack two into one u32
__device__ __forceinline__ uint32_t pk_bf16(float a, float b) {
    uint32_t ua = __builtin_bit_cast(uint32_t, a) + 0x8000u;
    uint32_t ub = __builtin_bit_cast(uint32_t, b) + 0x8000u;
    return (ua >> 16) | (ub & 0xFFFF0000u);
}

// ---------------------------------------------------------------------------
// Per-row: r[row] = 1/max(||X[row]||,eps); Xb[row,:] = bf16(X[row,:] * r).
// One wave per row, 4 rows / 256-thread block.
// ---------------------------------------------------------------------------
__global__ __launch_bounds__(256) void convert_norm_kernel(
        const float* __restrict__ X, unsigned short* __restrict__ Xb,
        float* __restrict__ r, int R) {
    int row = blockIdx.x * 4 + (threadIdx.x >> 6);
    if (row >= R) return;
    int lane = threadIdx.x & 63;
    const float* x = X + (size_t)row * D_DIM + lane * 8;
    float4 f0 = *(const float4*)(x);
    float4 f1 = *(const float4*)(x + 4);
    float s = f0.x*f0.x + f0.y*f0.y + f0.z*f0.z + f0.w*f0.w
            + f1.x*f1.x + f1.y*f1.y + f1.z*f1.z + f1.w*f1.w;
#pragma unroll
    for (int off = 32; off; off >>= 1) s += __shfl_xor(s, off);
    float rv = 1.0f / fmaxf(sqrtf(s), 1e-12f);
    if (lane == 0) r[row] = rv;
    uint4 w;
    w.x = pk_bf16(f0.x * rv, f0.y * rv);
    w.y = pk_bf16(f0.z * rv, f0.w * rv);
    w.z = pk_bf16(f1.x * rv, f1.y * rv);
    w.w = pk_bf16(f1.z * rv, f1.w * rv);
    *(uint4*)(Xb + (size_t)row * D_DIM + lane * 8) = w;
}

// ---------------------------------------------------------------------------
// m97-structure bf16 GEMM: sim = Zb . Pb^T   (inputs pre-normalized bf16)
// 128x128 tile, 4 waves (2x2), 4x4 frags of mfma_f32_16x16x32_bf16, BK=64.
// global_load_lds width-16 staging; chunk-XOR swizzle applied on the global
// source (write side) and on ds_read (read side) -> conflict-free.
// ---------------------------------------------------------------------------
__global__ __launch_bounds__(256) void gemm_lds_bf16(
        const unsigned short* __restrict__ Zb,
        const unsigned short* __restrict__ Pb,
        float* __restrict__ sim, int Pn) {
    __shared__ uint4 S[2048];   // A: [0..1023], B: [1024..2047]; 16B chunks

    int bi = blockIdx.x;
    int mb, nb;
    if (gridDim.x == 16384) {            // XCD band mapping (B=8192,P=32768)
        int xcd = bi & 7;
        int r = bi >> 3;
        mb = xcd * 8 + (r & 7);          // 0..63
        nb = r >> 3;                     // 0..255
    } else {
        nb = bi % (Pn / 128);
        mb = bi / (Pn / 128);
    }
    const int bm = mb * 128, bn = nb * 128;

    const int tid = threadIdx.x;
    const int lane = tid & 63;
    const int wid = tid >> 6;
    const int wr = wid >> 1, wc = wid & 1;
    const int ln15 = lane & 15, hi = lane >> 4;

    // staging: 4 issues of 256 lanes x 16B each for A and B per K-step
    const unsigned short* gA[4];
    const unsigned short* gB[4];
    int ldsIdx[4];
#pragma unroll
    for (int q = 0; q < 4; ++q) {
        int flat = q * 256 + tid;        // 16B-chunk id: row*8 + c
        int row = flat >> 3;
        int c = flat & 7;
        int cg = c ^ (row & 7);          // pre-swizzled global chunk
        gA[q] = Zb + (size_t)(bm + row) * D_DIM + cg * 8;
        gB[q] = Pb + (size_t)(bn + row) * D_DIM + cg * 8;
        ldsIdx[q] = flat;                // linear LDS dest
    }

    f32x4 acc[4][4] = {};

#pragma unroll 1
    for (int s8 = 0; s8 < 8; ++s8) {
#pragma unroll
        for (int q = 0; q < 4; ++q) {
            GLD_LDS16(gA[q], &S[ldsIdx[q]]);
            GLD_LDS16(gB[q], &S[1024 + ldsIdx[q]]);
            gA[q] += 64;                 // next K-slab (64 bf16)
            gB[q] += 64;
        }
        asm volatile("s_waitcnt vmcnt(0)" ::: "memory");
        __syncthreads();

#pragma unroll
        for (int kk = 0; kk < 2; ++kk) {
            bf16x8 av[4], bv[4];
            const int kch = kk * 4 + hi;
#pragma unroll
            for (int t = 0; t < 4; ++t) {
                int arow = wr * 64 + t * 16 + ln15;
                av[t] = __builtin_bit_cast(bf16x8,
                        S[arow * 8 + (kch ^ (arow & 7))]);
                int brow = wc * 64 + t * 16 + ln15;
                bv[t] = __builtin_bit_cast(bf16x8,
                        S[1024 + brow * 8 + (kch ^ (brow & 7))]);
            }
#pragma unroll
            for (int i = 0; i < 4; ++i)
#pragma unroll
                for (int j = 0; j < 4; ++j)
                    acc[i][j] = __builtin_amdgcn_mfma_f32_16x16x32_bf16(
                        av[i], bv[j], acc[i][j], 0, 0, 0);
        }
        __syncthreads();
    }

    // epilogue: C/D layout col=lane&15, row=(lane>>4)*4+reg
#pragma unroll
    for (int i = 0; i < 4; ++i) {
#pragma unroll
        for (int rr = 0; rr < 4; ++rr) {
            int row = bm + wr * 64 + i * 16 + hi * 4 + rr;
#pragma unroll
            for (int j = 0; j < 4; ++j) {
                int col = bn + wc * 64 + j * 16 + ln15;
                sim[(size_t)row * Pn + col] = acc[i][j][rr];
            }
        }
    }
}

// ---------------------------------------------------------------------------
// FALLBACK (ws too small): round-2 reg-staging GEMM with epilogue scaling.
// ---------------------------------------------------------------------------
__global__ __launch_bounds__(256) void rnorm_kernel(const float* __restrict__ X,
                                                    float* __restrict__ r, int R) {
    int row = blockIdx.x * 4 + (threadIdx.x >> 6);
    if (row >= R) return;
    int lane = threadIdx.x & 63;
    const float* x = X + (size_t)row * D_DIM;
    float s = 0.f;
#pragma unroll
    for (int t = 0; t < 2; ++t) {
        float4 v = *(const float4*)(x + (t * 64 + lane) * 4);
        s += v.x * v.x + v.y * v.y + v.z * v.z + v.w * v.w;
    }
#pragma unroll
    for (int off = 32; off; off >>= 1) s += __shfl_xor(s, off);
    if (lane == 0) r[row] = 1.0f / fmaxf(sqrtf(s), 1e-12f);
}

__global__ __launch_bounds__(256, 2) void gemm_bf16_sim(const float* __restrict__ Z,
        const float* __restrict__ Pm, const float* __restrict__ rz,
        const float* __restrict__ rp, float* __restrict__ sim, int Pn) {
    __shared__ uint4 As16[1024];
    __shared__ uint4 Bs16[1024];
    int bi = blockIdx.x;
    int mb, nb;
    if (gridDim.x == 16384) {
        int xcd = bi & 7;
        int r = bi >> 3;
        mb = xcd * 8 + (r & 7);
        nb = r >> 3;
    } else {
        nb = bi % (Pn / 128);
        mb = bi / (Pn / 128);
    }
    const int bm = mb * 128, bn = nb * 128;
    const int tid = threadIdx.x;
    const int srow = tid >> 1;
    const int half = tid & 1;
    const float* aP = Z  + (size_t)(bm + srow) * D_DIM + half * 32;
    const float* bP = Pm + (size_t)(bn + srow) * D_DIM + half * 32;
    const int lane = tid & 63;
    const int wid = tid >> 6;
    const int wr = wid >> 1, wc = wid & 1;
    const int ln15 = lane & 15, hi = lane >> 4;
    f32x4 acc[4][4] = {};
    float4 f[8], g[8];
#pragma unroll
    for (int q = 0; q < 8; ++q) {
        f[q] = *(const float4*)(aP + q * 4);
        g[q] = *(const float4*)(bP + q * 4);
    }
#pragma unroll 1
    for (int s = 0; s < 8; ++s) {
#pragma unroll
        for (int q8 = 0; q8 < 4; ++q8) {
            uint4 wa, wb;
            wa.x = pk_bf16(f[2*q8].x,   f[2*q8].y);
            wa.y = pk_bf16(f[2*q8].z,   f[2*q8].w);
            wa.z = pk_bf16(f[2*q8+1].x, f[2*q8+1].y);
            wa.w = pk_bf16(f[2*q8+1].z, f[2*q8+1].w);
            wb.x = pk_bf16(g[2*q8].x,   g[2*q8].y);
            wb.y = pk_bf16(g[2*q8].z,   g[2*q8].w);
            wb.z = pk_bf16(g[2*q8+1].x, g[2*q8+1].y);
            wb.w = pk_bf16(g[2*q8+1].z, g[2*q8+1].w);
            int colByte = half * 64 + q8 * 16;
            int idx = srow * 8 + ((colByte ^ ((srow & 7) << 4)) >> 4);
            As16[idx] = wa;
            Bs16[idx] = wb;
        }
        __syncthreads();
        if (s < 7) {
            int k0 = (s + 1) * 64;
#pragma unroll
            for (int q = 0; q < 8; ++q) {
                f[q] = *(const float4*)(aP + k0 + q * 4);
                g[q] = *(const float4*)(bP + k0 + q * 4);
            }
        }
#pragma unroll
        for (int kk = 0; kk < 2; ++kk) {
            bf16x8 av[4], bv[4];
            const int cb = kk * 64 + hi * 16;
#pragma unroll
            for (int t = 0; t < 4; ++t) {
                int arow = wr * 64 + t * 16 + ln15;
                av[t] = __builtin_bit_cast(bf16x8,
                        As16[arow * 8 + ((cb ^ ((arow & 7) << 4)) >> 4)]);
                int brow = wc * 64 + t * 16 + ln15;
                bv[t] = __builtin_bit_cast(bf16x8,
                        Bs16[brow * 8 + ((cb ^ ((brow & 7) << 4)) >> 4)]);
            }
#pragma unroll
            for (int i = 0; i < 4; ++i)
#pragma unroll
                for (int j = 0; j < 4; ++j)
                    acc[i][j] = __builtin_amdgcn_mfma_f32_16x16x32_bf16(
                        av[i], bv[j], acc[i][j], 0, 0, 0);
        }
        __syncthreads();
    }
    float rpv[4];
#pragma unroll
    for (int j = 0; j < 4; ++j) rpv[j] = rp[bn + wc * 64 + j * 16 + ln15];
#pragma unroll
    for (int i = 0; i < 4; ++i) {
#pragma unroll
        for (int rr = 0; rr < 4; ++rr) {
            int row = bm + wr * 64 + i * 16 + hi * 4 + rr;
            float rzv = rz[row];
#pragma unroll
            for (int j = 0; j < 4; ++j) {
                int col = bn + wc * 64 + j * 16 + ln15;
                sim[(size_t)row * Pn + col] = acc[i][j][rr] * rzv * rpv[j];
            }
        }
    }
}

// ---------------------------------------------------------------------------
// Top-3 with exact refinement (noisy top-8 candidates -> exact f32 rerank).
// ---------------------------------------------------------------------------
__global__ __launch_bounds__(256) void topk_refine(const float* __restrict__ sim,
        const float* __restrict__ Z, const float* __restrict__ Pm,
        const float* __restrict__ rz, const float* __restrict__ rp,
        float* __restrict__ oidx, float* __restrict__ oval, int Pn) {
    int row = blockIdx.x * 4 + (threadIdx.x >> 6);
    int lane = threadIdx.x & 63;
    const float* rptr = sim + (size_t)row * Pn;

    float v[8]; int ix[8];
#pragma unroll
    for (int j = 0; j < 8; ++j) { v[j] = -FLT_MAX; ix[j] = -1; }

    const int iters = Pn >> 8;
    for (int t = 0; t < iters; ++t) {
        int base = t * 256 + lane * 4;
        float4 q = *(const float4*)(rptr + base);
        float vals[4] = {q.x, q.y, q.z, q.w};
#pragma unroll
        for (int e = 0; e < 4; ++e) {
            float val = vals[e];
            if (val > v[7]) {
                int idx = base + e;
                int pos = 7;
#pragma unroll
                for (int j = 6; j >= 0; --j) {
                    if (val > v[j]) { v[j+1] = v[j]; ix[j+1] = ix[j]; pos = j; }
                }
                v[pos] = val; ix[pos] = idx;
            }
        }
    }

    int cand[8];
#pragma unroll
    for (int k = 0; k < 8; ++k) {
        float bv = v[0]; int bi2 = ix[0];
#pragma unroll
        for (int off = 32; off; off >>= 1) {
            float ov = __shfl_xor(bv, off);
            int oi = __shfl_xor(bi2, off);
            if (ov > bv || (ov == bv && oi >= 0 && (unsigned)oi < (unsigned)bi2)) {
                bv = ov; bi2 = oi;
            }
        }
        cand[k] = bi2;
        if (bi2 == ix[0]) {
#pragma unroll
            for (int j = 0; j < 7; ++j) { v[j] = v[j+1]; ix[j] = ix[j+1]; }
            v[7] = -FLT_MAX; ix[7] = -1;
        }
    }

    float zv[8];
    const float* zrow = Z + (size_t)row * D_DIM + lane * 8;
#pragma unroll
    for (int j = 0; j < 8; ++j) zv[j] = zrow[j];
    float rzv = rz[row];

    float ex[8];
#pragma unroll
    for (int c = 0; c < 8; ++c) {
        int idx = cand[c];
        const float* prow = Pm + (size_t)idx * D_DIM + lane * 8;
        float s = 0.f;
#pragma unroll
        for (int j = 0; j < 8; ++j) s += zv[j] * prow[j];
#pragma unroll
        for (int off = 32; off; off >>= 1) s += __shfl_xor(s, off);
        ex[c] = s * rzv * rp[idx];
    }

    bool used[8] = {};
#pragma unroll
    for (int k = 0; k < 3; ++k) {
        float bv = -FLT_MAX; int bi2 = Pn; int bc = 0;
#pragma unroll
        for (int c = 0; c < 8; ++c) {
            if (!used[c] && (ex[c] > bv || (ex[c] == bv && cand[c] < bi2))) {
                bv = ex[c]; bi2 = cand[c]; bc = c;
            }
        }
        used[bc] = true;
        if (lane == 0) {
            oidx[(size_t)row * 3 + k] = (float)bi2;
            oval[(size_t)row * 3 + k] = bv;
        }
    }
}

extern "C" void kernel_launch(void* const* d_in, const int* in_sizes, int n_in,
                              void* d_out, int out_size, void* d_ws, size_t ws_size,
                              hipStream_t stream) {
    const float* Z  = (const float*)d_in[0];   // [B, 512]
    const float* Pm = (const float*)d_in[1];   // [P, 512]
    const int B  = in_sizes[0] / D_DIM;        // 8192
    const int Pn = in_sizes[1] / D_DIM;        // 32768

    float* sim  = (float*)d_out;
    float* oidx = sim + (size_t)B * Pn;
    float* oval = oidx + (size_t)B * 3;

    float* rz = (float*)d_ws;
    float* rp = rz + B;

    size_t need = (size_t)(B + Pn) * 4 + (size_t)(B + Pn) * D_DIM * 2;
    if (ws_size >= need) {
        unsigned short* Zb = (unsigned short*)(rp + Pn);
        unsigned short* Pb = Zb + (size_t)B * D_DIM;
        convert_norm_kernel<<<B / 4, 256, 0, stream>>>(Z, Zb, rz, B);
        convert_norm_kernel<<<Pn / 4, 256, 0, stream>>>(Pm, Pb, rp, Pn);
        gemm_lds_bf16<<<(B / 128) * (Pn / 128), 256, 0, stream>>>(Zb, Pb, sim, Pn);
    } else {
        rnorm_kernel<<<B / 4, 256, 0, stream>>>(Z, rz, B);
        rnorm_kernel<<<Pn / 4, 256, 0, stream>>>(Pm, rp, Pn);
        gemm_bf16_sim<<<(B / 128) * (Pn / 128), 256, 0, stream>>>(Z, Pm, rz, rp, sim, Pn);
    }
    topk_refine<<<B / 4, 256, 0, stream>>>(sim, Z, Pm, rz, rp, oidx, oval, Pn);
}

// Round 4
// 745.941 us; speedup vs baseline: 5.3559x; 1.1708x over previous
//
#include <hip/hip_runtime.h>
#include <float.h>
#include <stdint.h>

#define D_DIM 512

typedef __attribute__((ext_vector_type(8))) short bf16x8;
typedef __attribute__((ext_vector_type(4))) float f32x4;

// async global->LDS, 16B per lane (linear LDS dest: wave base + lane*16)
#define GLD_LDS16(g, l)                                              \
    __builtin_amdgcn_global_load_lds(                                \
        (const __attribute__((address_space(1))) void*)(g),          \
        (__attribute__((address_space(3))) void*)(l), 16, 0, 0)

// round-half-up f32->bf16, pack two into one u32
__device__ __forceinline__ uint32_t pk_bf16(float a, float b) {
    uint32_t ua = __builtin_bit_cast(uint32_t, a) + 0x8000u;
    uint32_t ub = __builtin_bit_cast(uint32_t, b) + 0x8000u;
    return (ua >> 16) | (ub & 0xFFFF0000u);
}

// ---------------------------------------------------------------------------
// Per-row: r[row] = 1/max(||X[row]||,eps); Xb[row,:] = bf16(X[row,:] * r).
// ---------------------------------------------------------------------------
__global__ __launch_bounds__(256) void convert_norm_kernel(
        const float* __restrict__ X, unsigned short* __restrict__ Xb,
        float* __restrict__ r, int R) {
    int row = blockIdx.x * 4 + (threadIdx.x >> 6);
    if (row >= R) return;
    int lane = threadIdx.x & 63;
    const float* x = X + (size_t)row * D_DIM + lane * 8;
    float4 f0 = *(const float4*)(x);
    float4 f1 = *(const float4*)(x + 4);
    float s = f0.x*f0.x + f0.y*f0.y + f0.z*f0.z + f0.w*f0.w
            + f1.x*f1.x + f1.y*f1.y + f1.z*f1.z + f1.w*f1.w;
#pragma unroll
    for (int off = 32; off; off >>= 1) s += __shfl_xor(s, off);
    float rv = 1.0f / fmaxf(sqrtf(s), 1e-12f);
    if (lane == 0) r[row] = rv;
    uint4 w;
    w.x = pk_bf16(f0.x * rv, f0.y * rv);
    w.y = pk_bf16(f0.z * rv, f0.w * rv);
    w.z = pk_bf16(f1.x * rv, f1.y * rv);
    w.w = pk_bf16(f1.z * rv, f1.w * rv);
    *(uint4*)(Xb + (size_t)row * D_DIM + lane * 8) = w;
}

// ---------------------------------------------------------------------------
// m97-structure bf16 GEMM (+ optional fused per-tile top-4 extraction).
// 128x128 tile, 4 waves (2x2), 4x4 frags of mfma_f32_16x16x32_bf16, BK=64.
// FUSE: after sim write, LDS-transpose the tile ([col][row+pad]) in two
// 64-row phases; each thread scans one (row, 32-col quarter) for top-4;
// 4 quarters merged via LDS; top-4 (val,idx) per row per 128-tile -> part.
// ---------------------------------------------------------------------------
template <bool FUSE>
__global__ __launch_bounds__(256) void gemm_lds_bf16(
        const unsigned short* __restrict__ Zb,
        const unsigned short* __restrict__ Pb,
        float* __restrict__ sim, uint2* __restrict__ part, int Pn) {
    constexpr int SH_BYTES = FUSE ? 43008 : 32768;
    __shared__ __align__(16) unsigned char SH[SH_BYTES];
    uint4* S = (uint4*)SH;   // staging: A [0..1023], B [1024..2047]

    int bi = blockIdx.x;
    int mb, nb;
    if (gridDim.x == 16384) {            // XCD band mapping (B=8192,P=32768)
        int xcd = bi & 7;
        int r = bi >> 3;
        mb = xcd * 8 + (r & 7);          // 0..63
        nb = r >> 3;                     // 0..255
    } else {
        nb = bi % (Pn / 128);
        mb = bi / (Pn / 128);
    }
    const int bm = mb * 128, bn = nb * 128;

    const int tid = threadIdx.x;
    const int lane = tid & 63;
    const int wid = tid >> 6;
    const int wr = wid >> 1, wc = wid & 1;
    const int ln15 = lane & 15, hi = lane >> 4;

    const unsigned short* gA[4];
    const unsigned short* gB[4];
    int ldsIdx[4];
#pragma unroll
    for (int q = 0; q < 4; ++q) {
        int flat = q * 256 + tid;        // 16B-chunk id: row*8 + c
        int row = flat >> 3;
        int c = flat & 7;
        int cg = c ^ (row & 7);          // pre-swizzled global chunk
        gA[q] = Zb + (size_t)(bm + row) * D_DIM + cg * 8;
        gB[q] = Pb + (size_t)(bn + row) * D_DIM + cg * 8;
        ldsIdx[q] = flat;
    }

    f32x4 acc[4][4] = {};

#pragma unroll 1
    for (int s8 = 0; s8 < 8; ++s8) {
#pragma unroll
        for (int q = 0; q < 4; ++q) {
            GLD_LDS16(gA[q], &S[ldsIdx[q]]);
            GLD_LDS16(gB[q], &S[1024 + ldsIdx[q]]);
            gA[q] += 64;
            gB[q] += 64;
        }
        asm volatile("s_waitcnt vmcnt(0)" ::: "memory");
        __syncthreads();

#pragma unroll
        for (int kk = 0; kk < 2; ++kk) {
            bf16x8 av[4], bv[4];
            const int kch = kk * 4 + hi;
#pragma unroll
            for (int t = 0; t < 4; ++t) {
                int arow = wr * 64 + t * 16 + ln15;
                av[t] = __builtin_bit_cast(bf16x8,
                        S[arow * 8 + (kch ^ (arow & 7))]);
                int brow = wc * 64 + t * 16 + ln15;
                bv[t] = __builtin_bit_cast(bf16x8,
                        S[1024 + brow * 8 + (kch ^ (brow & 7))]);
            }
#pragma unroll
            for (int i = 0; i < 4; ++i)
#pragma unroll
                for (int j = 0; j < 4; ++j)
                    acc[i][j] = __builtin_amdgcn_mfma_f32_16x16x32_bf16(
                        av[i], bv[j], acc[i][j], 0, 0, 0);
        }
        __syncthreads();
    }

    // sim write: C/D layout col=lane&15, row=(lane>>4)*4+reg
#pragma unroll
    for (int i = 0; i < 4; ++i) {
#pragma unroll
        for (int rr = 0; rr < 4; ++rr) {
            int row = bm + wr * 64 + i * 16 + hi * 4 + rr;
#pragma unroll
            for (int j = 0; j < 4; ++j) {
                int col = bn + wc * 64 + j * 16 + ln15;
                sim[(size_t)row * Pn + col] = acc[i][j][rr];
            }
        }
    }

    if constexpr (FUSE) {
        float* T = (float*)SH;               // [128 cols][68] f32 = 34816 B
        uint2* M = (uint2*)(SH + 34816);     // [4 q][4 k][64 r] = 8192 B
        const int NB = Pn >> 7;
        const int r = tid & 63;
        const int q = wid;
#pragma unroll 1
        for (int hf = 0; hf < 2; ++hf) {
            __syncthreads();
            if (wr == hf) {
#pragma unroll
                for (int i = 0; i < 4; ++i)
#pragma unroll
                    for (int j = 0; j < 4; ++j)
                        *(f32x4*)&T[(wc * 64 + j * 16 + ln15) * 68 + i * 16 + hi * 4]
                            = acc[i][j];
            }
            __syncthreads();
            // scan: thread -> (row r, quarter q); top-4 of 32 cols
            float tv[4]; int ti[4];
#pragma unroll
            for (int k = 0; k < 4; ++k) { tv[k] = -FLT_MAX; ti[k] = 0x7FFFFFFF; }
#pragma unroll
            for (int c = 0; c < 32; ++c) {
                float val = T[(q * 32 + c) * 68 + r];
                if (val > tv[3]) {
                    int p = 3;
#pragma unroll
                    for (int j2 = 2; j2 >= 0; --j2)
                        if (val > tv[j2]) { tv[j2+1] = tv[j2]; ti[j2+1] = ti[j2]; p = j2; }
                    tv[p] = val; ti[p] = bn + q * 32 + c;
                }
            }
#pragma unroll
            for (int k = 0; k < 4; ++k)
                M[q * 256 + k * 64 + r] =
                    make_uint2(__builtin_bit_cast(uint32_t, tv[k]), (uint32_t)ti[k]);
            __syncthreads();
            if (tid < 64) {   // merge 4 quarters -> row top-4, write partials
                float fv[4]; int fi[4];
#pragma unroll
                for (int k = 0; k < 4; ++k) { fv[k] = -FLT_MAX; fi[k] = 0x7FFFFFFF; }
#pragma unroll
                for (int qq = 0; qq < 4; ++qq)
#pragma unroll
                    for (int k = 0; k < 4; ++k) {
                        uint2 u = M[qq * 256 + k * 64 + tid];
                        float val = __builtin_bit_cast(float, u.x);
                        if (val > fv[3]) {
                            int p = 3;
#pragma unroll
                            for (int j2 = 2; j2 >= 0; --j2)
                                if (val > fv[j2]) { fv[j2+1] = fv[j2]; fi[j2+1] = fi[j2]; p = j2; }
                            fv[p] = val; fi[p] = (int)u.y;
                        }
                    }
                size_t o = ((size_t)(bm + hf * 64 + tid) * NB + nb) * 4;
#pragma unroll
                for (int k = 0; k < 4; ++k)
                    part[o + k] =
                        make_uint2(__builtin_bit_cast(uint32_t, fv[k]), (uint32_t)fi[k]);
            }
        }
    }
}

// ---------------------------------------------------------------------------
// Reduce partial candidates (NB*4 per row) -> noisy top-8 -> exact f32
// rerank -> top-3. One wave per row.
// ---------------------------------------------------------------------------
__global__ __launch_bounds__(256) void topk_reduce(const uint2* __restrict__ part,
        const float* __restrict__ Z, const float* __restrict__ Pm,
        const float* __restrict__ rz, const float* __restrict__ rp,
        float* __restrict__ oidx, float* __restrict__ oval, int Pn) {
    int row = blockIdx.x * 4 + (threadIdx.x >> 6);
    int lane = threadIdx.x & 63;
    const int NB = Pn >> 7;
    const uint2* pr = part + (size_t)row * NB * 4;

    float v[8]; int ix[8];
#pragma unroll
    for (int j = 0; j < 8; ++j) { v[j] = -FLT_MAX; ix[j] = -1; }

    const int total = NB * 4;
    for (int c = lane; c < total; c += 64) {
        uint2 u = pr[c];
        float val = __builtin_bit_cast(float, u.x);
        if (val > v[7]) {
            int idx = (int)u.y;
            int pos = 7;
#pragma unroll
            for (int j = 6; j >= 0; --j) {
                if (val > v[j]) { v[j+1] = v[j]; ix[j+1] = ix[j]; pos = j; }
            }
            v[pos] = val; ix[pos] = idx;
        }
    }

    int cand[8];
#pragma unroll
    for (int k = 0; k < 8; ++k) {
        float bv = v[0]; int bi2 = ix[0];
#pragma unroll
        for (int off = 32; off; off >>= 1) {
            float ov = __shfl_xor(bv, off);
            int oi = __shfl_xor(bi2, off);
            if (ov > bv || (ov == bv && oi >= 0 && (unsigned)oi < (unsigned)bi2)) {
                bv = ov; bi2 = oi;
            }
        }
        cand[k] = bi2;
        if (bi2 == ix[0]) {
#pragma unroll
            for (int j = 0; j < 7; ++j) { v[j] = v[j+1]; ix[j] = ix[j+1]; }
            v[7] = -FLT_MAX; ix[7] = -1;
        }
    }

    // exact f32 recompute of the 8 candidate similarities
    float zv[8];
    const float* zrow = Z + (size_t)row * D_DIM + lane * 8;
#pragma unroll
    for (int j = 0; j < 8; ++j) zv[j] = zrow[j];
    float rzv = rz[row];

    float ex[8];
#pragma unroll
    for (int c = 0; c < 8; ++c) {
        int idx = cand[c];
        const float* prow = Pm + (size_t)idx * D_DIM + lane * 8;
        float s = 0.f;
#pragma unroll
        for (int j = 0; j < 8; ++j) s += zv[j] * prow[j];
#pragma unroll
        for (int off = 32; off; off >>= 1) s += __shfl_xor(s, off);
        ex[c] = s * rzv * rp[idx];
    }

    bool used[8] = {};
#pragma unroll
    for (int k = 0; k < 3; ++k) {
        float bv = -FLT_MAX; int bi2 = Pn; int bc = 0;
#pragma unroll
        for (int c = 0; c < 8; ++c) {
            if (!used[c] && (ex[c] > bv || (ex[c] == bv && cand[c] < bi2))) {
                bv = ex[c]; bi2 = cand[c]; bc = c;
            }
        }
        used[bc] = true;
        if (lane == 0) {
            oidx[(size_t)row * 3 + k] = (float)bi2;
            oval[(size_t)row * 3 + k] = bv;
        }
    }
}

// ---------------------------------------------------------------------------
// Fallbacks (smaller ws): round-3 topk over sim, round-2 f32-input GEMM.
// ---------------------------------------------------------------------------
__global__ __launch_bounds__(256) void rnorm_kernel(const float* __restrict__ X,
                                                    float* __restrict__ r, int R) {
    int row = blockIdx.x * 4 + (threadIdx.x >> 6);
    if (row >= R) return;
    int lane = threadIdx.x & 63;
    const float* x = X + (size_t)row * D_DIM;
    float s = 0.f;
#pragma unroll
    for (int t = 0; t < 2; ++t) {
        float4 v = *(const float4*)(x + (t * 64 + lane) * 4);
        s += v.x * v.x + v.y * v.y + v.z * v.z + v.w * v.w;
    }
#pragma unroll
    for (int off = 32; off; off >>= 1) s += __shfl_xor(s, off);
    if (lane == 0) r[row] = 1.0f / fmaxf(sqrtf(s), 1e-12f);
}

__global__ __launch_bounds__(256, 2) void gemm_bf16_sim(const float* __restrict__ Z,
        const float* __restrict__ Pm, const float* __restrict__ rz,
        const float* __restrict__ rp, float* __restrict__ sim, int Pn) {
    __shared__ uint4 As16[1024];
    __shared__ uint4 Bs16[1024];
    int bi = blockIdx.x;
    int mb, nb;
    if (gridDim.x == 16384) {
        int xcd = bi & 7;
        int r = bi >> 3;
        mb = xcd * 8 + (r & 7);
        nb = r >> 3;
    } else {
        nb = bi % (Pn / 128);
        mb = bi / (Pn / 128);
    }
    const int bm = mb * 128, bn = nb * 128;
    const int tid = threadIdx.x;
    const int srow = tid >> 1;
    const int half = tid & 1;
    const float* aP = Z  + (size_t)(bm + srow) * D_DIM + half * 32;
    const float* bP = Pm + (size_t)(bn + srow) * D_DIM + half * 32;
    const int lane = tid & 63;
    const int wid = tid >> 6;
    const int wr = wid >> 1, wc = wid & 1;
    const int ln15 = lane & 15, hi = lane >> 4;
    f32x4 acc[4][4] = {};
    float4 f[8], g[8];
#pragma unroll
    for (int q = 0; q < 8; ++q) {
        f[q] = *(const float4*)(aP + q * 4);
        g[q] = *(const float4*)(bP + q * 4);
    }
#pragma unroll 1
    for (int s = 0; s < 8; ++s) {
#pragma unroll
        for (int q8 = 0; q8 < 4; ++q8) {
            uint4 wa, wb;
            wa.x = pk_bf16(f[2*q8].x,   f[2*q8].y);
            wa.y = pk_bf16(f[2*q8].z,   f[2*q8].w);
            wa.z = pk_bf16(f[2*q8+1].x, f[2*q8+1].y);
            wa.w = pk_bf16(f[2*q8+1].z, f[2*q8+1].w);
            wb.x = pk_bf16(g[2*q8].x,   g[2*q8].y);
            wb.y = pk_bf16(g[2*q8].z,   g[2*q8].w);
            wb.z = pk_bf16(g[2*q8+1].x, g[2*q8+1].y);
            wb.w = pk_bf16(g[2*q8+1].z, g[2*q8+1].w);
            int colByte = half * 64 + q8 * 16;
            int idx = srow * 8 + ((colByte ^ ((srow & 7) << 4)) >> 4);
            As16[idx] = wa;
            Bs16[idx] = wb;
        }
        __syncthreads();
        if (s < 7) {
            int k0 = (s + 1) * 64;
#pragma unroll
            for (int q = 0; q < 8; ++q) {
                f[q] = *(const float4*)(aP + k0 + q * 4);
                g[q] = *(const float4*)(bP + k0 + q * 4);
            }
        }
#pragma unroll
        for (int kk = 0; kk < 2; ++kk) {
            bf16x8 av[4], bv[4];
            const int cb = kk * 64 + hi * 16;
#pragma unroll
            for (int t = 0; t < 4; ++t) {
                int arow = wr * 64 + t * 16 + ln15;
                av[t] = __builtin_bit_cast(bf16x8,
                        As16[arow * 8 + ((cb ^ ((arow & 7) << 4)) >> 4)]);
                int brow = wc * 64 + t * 16 + ln15;
                bv[t] = __builtin_bit_cast(bf16x8,
                        Bs16[brow * 8 + ((cb ^ ((brow & 7) << 4)) >> 4)]);
            }
#pragma unroll
            for (int i = 0; i < 4; ++i)
#pragma unroll
                for (int j = 0; j < 4; ++j)
                    acc[i][j] = __builtin_amdgcn_mfma_f32_16x16x32_bf16(
                        av[i], bv[j], acc[i][j], 0, 0, 0);
        }
        __syncthreads();
    }
    float rpv[4];
#pragma unroll
    for (int j = 0; j < 4; ++j) rpv[j] = rp[bn + wc * 64 + j * 16 + ln15];
#pragma unroll
    for (int i = 0; i < 4; ++i) {
#pragma unroll
        for (int rr = 0; rr < 4; ++rr) {
            int row = bm + wr * 64 + i * 16 + hi * 4 + rr;
            float rzv = rz[row];
#pragma unroll
            for (int j = 0; j < 4; ++j) {
                int col = bn + wc * 64 + j * 16 + ln15;
                sim[(size_t)row * Pn + col] = acc[i][j][rr] * rzv * rpv[j];
            }
        }
    }
}

__global__ __launch_bounds__(256) void topk_refine(const float* __restrict__ sim,
        const float* __restrict__ Z, const float* __restrict__ Pm,
        const float* __restrict__ rz, const float* __restrict__ rp,
        float* __restrict__ oidx, float* __restrict__ oval, int Pn) {
    int row = blockIdx.x * 4 + (threadIdx.x >> 6);
    int lane = threadIdx.x & 63;
    const float* rptr = sim + (size_t)row * Pn;

    float v[8]; int ix[8];
#pragma unroll
    for (int j = 0; j < 8; ++j) { v[j] = -FLT_MAX; ix[j] = -1; }

    const int iters = Pn >> 8;
    for (int t = 0; t < iters; ++t) {
        int base = t * 256 + lane * 4;
        float4 q = *(const float4*)(rptr + base);
        float vals[4] = {q.x, q.y, q.z, q.w};
#pragma unroll
        for (int e = 0; e < 4; ++e) {
            float val = vals[e];
            if (val > v[7]) {
                int idx = base + e;
                int pos = 7;
#pragma unroll
                for (int j = 6; j >= 0; --j) {
                    if (val > v[j]) { v[j+1] = v[j]; ix[j+1] = ix[j]; pos = j; }
                }
                v[pos] = val; ix[pos] = idx;
            }
        }
    }

    int cand[8];
#pragma unroll
    for (int k = 0; k < 8; ++k) {
        float bv = v[0]; int bi2 = ix[0];
#pragma unroll
        for (int off = 32; off; off >>= 1) {
            float ov = __shfl_xor(bv, off);
            int oi = __shfl_xor(bi2, off);
            if (ov > bv || (ov == bv && oi >= 0 && (unsigned)oi < (unsigned)bi2)) {
                bv = ov; bi2 = oi;
            }
        }
        cand[k] = bi2;
        if (bi2 == ix[0]) {
#pragma unroll
            for (int j = 0; j < 7; ++j) { v[j] = v[j+1]; ix[j] = ix[j+1]; }
            v[7] = -FLT_MAX; ix[7] = -1;
        }
    }

    float zv[8];
    const float* zrow = Z + (size_t)row * D_DIM + lane * 8;
#pragma unroll
    for (int j = 0; j < 8; ++j) zv[j] = zrow[j];
    float rzv = rz[row];

    float ex[8];
#pragma unroll
    for (int c = 0; c < 8; ++c) {
        int idx = cand[c];
        const float* prow = Pm + (size_t)idx * D_DIM + lane * 8;
        float s = 0.f;
#pragma unroll
        for (int j = 0; j < 8; ++j) s += zv[j] * prow[j];
#pragma unroll
        for (int off = 32; off; off >>= 1) s += __shfl_xor(s, off);
        ex[c] = s * rzv * rp[idx];
    }

    bool used[8] = {};
#pragma unroll
    for (int k = 0; k < 3; ++k) {
        float bv = -FLT_MAX; int bi2 = Pn; int bc = 0;
#pragma unroll
        for (int c = 0; c < 8; ++c) {
            if (!used[c] && (ex[c] > bv || (ex[c] == bv && cand[c] < bi2))) {
                bv = ex[c]; bi2 = cand[c]; bc = c;
            }
        }
        used[bc] = true;
        if (lane == 0) {
            oidx[(size_t)row * 3 + k] = (float)bi2;
            oval[(size_t)row * 3 + k] = bv;
        }
    }
}

extern "C" void kernel_launch(void* const* d_in, const int* in_sizes, int n_in,
                              void* d_out, int out_size, void* d_ws, size_t ws_size,
                              hipStream_t stream) {
    const float* Z  = (const float*)d_in[0];   // [B, 512]
    const float* Pm = (const float*)d_in[1];   // [P, 512]
    const int B  = in_sizes[0] / D_DIM;        // 8192
    const int Pn = in_sizes[1] / D_DIM;        // 32768

    float* sim  = (float*)d_out;
    float* oidx = sim + (size_t)B * Pn;
    float* oval = oidx + (size_t)B * 3;

    float* rz = (float*)d_ws;
    float* rp = rz + B;
    unsigned short* Zb = (unsigned short*)(rp + Pn);
    unsigned short* Pb = Zb + (size_t)B * D_DIM;
    uint2* part = (uint2*)(Pb + (size_t)Pn * D_DIM);

    const size_t NB = (size_t)Pn / 128;
    const size_t need_bf16  = (size_t)(B + Pn) * 4 + (size_t)(B + Pn) * D_DIM * 2;
    const size_t need_fused = need_bf16 + (size_t)B * NB * 4 * sizeof(uint2);

    dim3 grid((B / 128) * (Pn / 128));

    if (ws_size >= need_fused) {
        convert_norm_kernel<<<B / 4, 256, 0, stream>>>(Z, Zb, rz, B);
        convert_norm_kernel<<<Pn / 4, 256, 0, stream>>>(Pm, Pb, rp, Pn);
        gemm_lds_bf16<true><<<grid, 256, 0, stream>>>(Zb, Pb, sim, part, Pn);
        topk_reduce<<<B / 4, 256, 0, stream>>>(part, Z, Pm, rz, rp, oidx, oval, Pn);
    } else if (ws_size >= need_bf16) {
        convert_norm_kernel<<<B / 4, 256, 0, stream>>>(Z, Zb, rz, B);
        convert_norm_kernel<<<Pn / 4, 256, 0, stream>>>(Pm, Pb, rp, Pn);
        gemm_lds_bf16<false><<<grid, 256, 0, stream>>>(Zb, Pb, sim, nullptr, Pn);
        topk_refine<<<B / 4, 256, 0, stream>>>(sim, Z, Pm, rz, rp, oidx, oval, Pn);
    } else {
        rnorm_kernel<<<B / 4, 256, 0, stream>>>(Z, rz, B);
        rnorm_kernel<<<Pn / 4, 256, 0, stream>>>(Pm, rp, Pn);
        gemm_bf16_sim<<<grid, 256, 0, stream>>>(Z, Pm, rz, rp, sim, Pn);
        topk_refine<<<B / 4, 256, 0, stream>>>(sim, Z, Pm, rz, rp, oidx, oval, Pn);
    }
}